// Round 1
// baseline (174.588 us; speedup 1.0000x reference)
//
#include <hip/hip_runtime.h>

#define H 1024
#define BSZ 64
#define TT 512
#define BT (BSZ * TT)   // 32768 rows
#define NSPLIT 8

using bf16x8 = __attribute__((ext_vector_type(8))) __bf16;
using f32x4  = __attribute__((ext_vector_type(4))) float;

__device__ __forceinline__ unsigned short f2bf(float f) {
  unsigned u = __float_as_uint(f);
  u += 0x7FFF + ((u >> 16) & 1);   // RTN-even
  return (unsigned short)(u >> 16);
}
__device__ __forceinline__ float bf2f(unsigned short h) {
  return __uint_as_float(((unsigned)h) << 16);
}

#define GLDS(gp, lp) \
  __builtin_amdgcn_global_load_lds( \
      (const __attribute__((address_space(1))) void*)(gp), \
      (__attribute__((address_space(3))) void*)(lp), 16, 0, 0)

// ---------------- Kernel 1: LayerNorm + bf16 cast ----------------
__global__ __launch_bounds__(256) void ln_kernel(
    const float* __restrict__ in, const float* __restrict__ gamma,
    const float* __restrict__ beta, unsigned short* __restrict__ xb) {
  const int row = blockIdx.x;
  const int tid = threadIdx.x;
  const float4 xv = reinterpret_cast<const float4*>(in + (size_t)row * H)[tid];
  float s  = xv.x + xv.y + xv.z + xv.w;
  float ss = xv.x * xv.x + xv.y * xv.y + xv.z * xv.z + xv.w * xv.w;
#pragma unroll
  for (int off = 32; off >= 1; off >>= 1) {
    s  += __shfl_xor(s, off);
    ss += __shfl_xor(ss, off);
  }
  __shared__ float red[2][4];
  const int w = tid >> 6;
  if ((tid & 63) == 0) { red[0][w] = s; red[1][w] = ss; }
  __syncthreads();
  const float tot  = red[0][0] + red[0][1] + red[0][2] + red[0][3];
  const float tot2 = red[1][0] + red[1][1] + red[1][2] + red[1][3];
  const float mu   = tot * (1.0f / H);
  const float var  = tot2 * (1.0f / H) - mu * mu;
  const float rstd = rsqrtf(var + 1e-5f);
  const float4 g  = reinterpret_cast<const float4*>(gamma)[tid];
  const float4 bt = reinterpret_cast<const float4*>(beta)[tid];
  ushort4 o;
  o.x = f2bf((xv.x - mu) * rstd * g.x + bt.x);
  o.y = f2bf((xv.y - mu) * rstd * g.y + bt.y);
  o.z = f2bf((xv.z - mu) * rstd * g.z + bt.z);
  o.w = f2bf((xv.w - mu) * rstd * g.w + bt.w);
  reinterpret_cast<ushort4*>(xb + (size_t)row * H)[tid] = o;
}

// ---------------- Kernel 2: W -> bf16 ----------------
__global__ __launch_bounds__(256) void wcvt_kernel(
    const float* __restrict__ Win, unsigned short* __restrict__ wb) {
  const size_t i = (size_t)blockIdx.x * 1024 + (size_t)threadIdx.x * 4;
  const float4 xv = *reinterpret_cast<const float4*>(Win + i);
  ushort4 o;
  o.x = f2bf(xv.x); o.y = f2bf(xv.y); o.z = f2bf(xv.z); o.w = f2bf(xv.w);
  *reinterpret_cast<ushort4*>(wb + i) = o;
}

// ---------------- Kernel 3: fused scores GEMM ----------------
// spart[nt][m] = sum over d in [nt*128, nt*128+128) of tanh(Wout[m,d]+bW[d])*v[d]
__global__ __launch_bounds__(256) void score_gemm(
    const unsigned short* __restrict__ xb, const unsigned short* __restrict__ wb,
    const float* __restrict__ bW, const float* __restrict__ v,
    float* __restrict__ spart) {
  __shared__ unsigned short Al[128 * 32];
  __shared__ unsigned short Bl[128 * 32];
  __shared__ float s_red[2][128];

  const int mt = blockIdx.x, nt = blockIdx.y;
  const int tid = threadIdx.x;
  const int w = tid >> 6, lane = tid & 63;
  const int wm = w >> 1, wn = w & 1;
  const int mbase = mt * 128, nbase = nt * 128;

  // staging: each call, wave w writes 1024B linear at Al+w*512 (lane*16B appended by HW)
  const int rr  = lane >> 2;          // 0..15
  const int kin = (lane & 3) * 8;     // 0,8,16,24 (bf16 units)
  const unsigned short* gA0 = xb + (size_t)(mbase +      w * 16 + rr) * H + kin;
  const unsigned short* gA1 = xb + (size_t)(mbase + 64 + w * 16 + rr) * H + kin;
  const unsigned short* gB0 = wb + (size_t)(nbase +      w * 16 + rr) * H + kin;
  const unsigned short* gB1 = wb + (size_t)(nbase + 64 + w * 16 + rr) * H + kin;

  f32x4 acc[4][4];
#pragma unroll
  for (int mi = 0; mi < 4; mi++)
#pragma unroll
    for (int ni = 0; ni < 4; ni++) acc[mi][ni] = (f32x4){0.f, 0.f, 0.f, 0.f};

  const int arow = wm * 64 + (lane & 15);
  const int brow = wn * 64 + (lane & 15);
  const int kcol = (lane >> 4) * 8;

  for (int kk = 0; kk < H; kk += 32) {
    GLDS(gA0 + kk, &Al[w * 512]);
    GLDS(gA1 + kk, &Al[(4 + w) * 512]);
    GLDS(gB0 + kk, &Bl[w * 512]);
    GLDS(gB1 + kk, &Bl[(4 + w) * 512]);
    __syncthreads();  // compiler drains vmcnt before s_barrier

    bf16x8 af[4], bfr[4];
#pragma unroll
    for (int mi = 0; mi < 4; mi++)
      af[mi] = *reinterpret_cast<const bf16x8*>(&Al[(arow + mi * 16) * 32 + kcol]);
#pragma unroll
    for (int ni = 0; ni < 4; ni++)
      bfr[ni] = *reinterpret_cast<const bf16x8*>(&Bl[(brow + ni * 16) * 32 + kcol]);
#pragma unroll
    for (int mi = 0; mi < 4; mi++)
#pragma unroll
      for (int ni = 0; ni < 4; ni++)
        acc[mi][ni] = __builtin_amdgcn_mfma_f32_16x16x32_bf16(af[mi], bfr[ni], acc[mi][ni], 0, 0, 0);
    __syncthreads();
  }

  // epilogue: tanh(.+bW)*v, reduce over columns
  float sp[4][4];
#pragma unroll
  for (int mi = 0; mi < 4; mi++)
#pragma unroll
    for (int r = 0; r < 4; r++) sp[mi][r] = 0.f;

#pragma unroll
  for (int ni = 0; ni < 4; ni++) {
    const int col = nbase + wn * 64 + ni * 16 + (lane & 15);
    const float bwv = bW[col];
    const float vv  = v[col];
#pragma unroll
    for (int mi = 0; mi < 4; mi++)
#pragma unroll
      for (int r = 0; r < 4; r++)
        sp[mi][r] += tanhf(acc[mi][ni][r] + bwv) * vv;
  }
  // reduce across the 16 lanes of each (lane>>4) group
#pragma unroll
  for (int mi = 0; mi < 4; mi++)
#pragma unroll
    for (int r = 0; r < 4; r++) {
      float sv = sp[mi][r];
      sv += __shfl_xor(sv, 1);
      sv += __shfl_xor(sv, 2);
      sv += __shfl_xor(sv, 4);
      sv += __shfl_xor(sv, 8);
      sp[mi][r] = sv;
    }
  if ((lane & 15) == 0) {
#pragma unroll
    for (int mi = 0; mi < 4; mi++)
#pragma unroll
      for (int r = 0; r < 4; r++)
        s_red[wn][wm * 64 + mi * 16 + (lane >> 4) * 4 + r] = sp[mi][r];
  }
  __syncthreads();
  if (tid < 128)
    spart[(size_t)nt * BT + mbase + tid] = s_red[0][tid] + s_red[1][tid];
}

// ---------------- Kernel 4: softmax over T per batch ----------------
__global__ __launch_bounds__(512) void softmax_kernel(
    const float* __restrict__ spart, const float* __restrict__ bv,
    float* __restrict__ wout) {
  const int b = blockIdx.x, t = threadIdx.x;
  float s = bv[0];
#pragma unroll
  for (int p = 0; p < NSPLIT; p++) s += spart[(size_t)p * BT + b * TT + t];
  if (s != s) s = 0.f;                       // nan_to_num
  s = fminf(fmaxf(s, -10.f), 10.f);          // clip
  float m = s;
#pragma unroll
  for (int off = 32; off >= 1; off >>= 1) m = fmaxf(m, __shfl_xor(m, off));
  __shared__ float redm[8], reds[8];
  const int w = t >> 6;
  if ((t & 63) == 0) redm[w] = m;
  __syncthreads();
  m = redm[0];
#pragma unroll
  for (int i = 1; i < 8; i++) m = fmaxf(m, redm[i]);
  const float e = expf(s - m);
  float su = e;
#pragma unroll
  for (int off = 32; off >= 1; off >>= 1) su += __shfl_xor(su, off);
  if ((t & 63) == 0) reds[w] = su;
  __syncthreads();
  su = 0.f;
#pragma unroll
  for (int i = 0; i < 8; i++) su += reds[i];
  wout[b * TT + t] = e / su;
}

// ---------------- Kernel 5: context partials over t-chunks ----------------
__global__ __launch_bounds__(256) void ctx_part_kernel(
    const unsigned short* __restrict__ xb, const float* __restrict__ wts,
    float* __restrict__ ctxp) {
  const int b = blockIdx.x, c = blockIdx.y, tid = threadIdx.x;
  const int h = tid * 4;
  float a0 = 0.f, a1 = 0.f, a2 = 0.f, a3 = 0.f;
  const unsigned short* xrow = xb + ((size_t)(b * TT + c * 64)) * H + h;
  const float* wrow = wts + b * TT + c * 64;
  for (int t = 0; t < 64; t++) {
    const float wgt = wrow[t];
    const ushort4 xv = *reinterpret_cast<const ushort4*>(xrow + (size_t)t * H);
    a0 += wgt * bf2f(xv.x);
    a1 += wgt * bf2f(xv.y);
    a2 += wgt * bf2f(xv.z);
    a3 += wgt * bf2f(xv.w);
  }
  float4 o = {a0, a1, a2, a3};
  *reinterpret_cast<float4*>(ctxp + ((size_t)c * BSZ + b) * H + h) = o;
}

// ---------------- Kernel 6: context reduce ----------------
__global__ __launch_bounds__(256) void ctx_reduce_kernel(
    const float* __restrict__ ctxp, float* __restrict__ out) {
  const int idx = blockIdx.x * 256 + threadIdx.x;  // 0..65535 = b*H+h
  float s = 0.f;
#pragma unroll
  for (int c = 0; c < 8; c++) s += ctxp[(size_t)c * (BSZ * H) + idx];
  out[idx] = s;
}

extern "C" void kernel_launch(void* const* d_in, const int* in_sizes, int n_in,
                              void* d_out, int out_size, void* d_ws, size_t ws_size,
                              hipStream_t stream) {
  const float* lstm  = (const float*)d_in[0];
  const float* W     = (const float*)d_in[1];
  const float* bW    = (const float*)d_in[2];
  const float* v     = (const float*)d_in[3];
  const float* bv    = (const float*)d_in[4];
  const float* gamma = (const float*)d_in[5];
  const float* beta  = (const float*)d_in[6];
  float* out = (float*)d_out;

  char* ws = (char*)d_ws;
  unsigned short* xb = (unsigned short*)ws;                                   // 64 MiB
  unsigned short* wb = (unsigned short*)(ws + (size_t)BT * H * 2);            // 2 MiB
  float* spart = (float*)(ws + (size_t)BT * H * 2 + (size_t)H * H * 2);       // 1 MiB
  float* ctxp  = (float*)((char*)spart + (size_t)NSPLIT * BT * 4);            // 2 MiB

  float* weights_out = out + BSZ * H;   // context first (65536), then weights (32768)

  ln_kernel<<<BT, 256, 0, stream>>>(lstm, gamma, beta, xb);
  wcvt_kernel<<<(H * H) / 1024, 256, 0, stream>>>(W, wb);
  score_gemm<<<dim3(BT / 128, NSPLIT), 256, 0, stream>>>(xb, wb, bW, v, spart);
  softmax_kernel<<<BSZ, TT, 0, stream>>>(spart, bv, weights_out);
  ctx_part_kernel<<<dim3(BSZ, 8), 256, 0, stream>>>(xb, weights_out, ctxp);
  ctx_reduce_kernel<<<(BSZ * H) / 256, 256, 0, stream>>>(ctxp, out);
}

// Round 2
// 134.584 us; speedup vs baseline: 1.2972x; 1.2972x over previous
//
#include <hip/hip_runtime.h>

#define H 1024
#define BSZ 64
#define TT 512
#define BT (BSZ * TT)   // 32768 rows
#define NSPLIT 4        // N=1024 / BN=256
#define NT 16           // K tiles = H / 64

using bf16x8 = __attribute__((ext_vector_type(8))) __bf16;
using f32x4  = __attribute__((ext_vector_type(4))) float;

__device__ __forceinline__ unsigned short f2bf(float f) {
  unsigned u = __float_as_uint(f);
  u += 0x7FFF + ((u >> 16) & 1);   // RTN-even
  return (unsigned short)(u >> 16);
}
__device__ __forceinline__ float bf2f(unsigned short h) {
  return __uint_as_float(((unsigned)h) << 16);
}

#define GLDS(gp, lp) \
  __builtin_amdgcn_global_load_lds( \
      (const __attribute__((address_space(1))) void*)(gp), \
      (__attribute__((address_space(3))) void*)(lp), 16, 0, 0)

// ---------------- Kernel 1: LayerNorm + bf16 cast ----------------
__global__ __launch_bounds__(256) void ln_kernel(
    const float* __restrict__ in, const float* __restrict__ gamma,
    const float* __restrict__ beta, unsigned short* __restrict__ xb) {
  const int row = blockIdx.x;
  const int tid = threadIdx.x;
  const float4 xv = reinterpret_cast<const float4*>(in + (size_t)row * H)[tid];
  float s  = xv.x + xv.y + xv.z + xv.w;
  float ss = xv.x * xv.x + xv.y * xv.y + xv.z * xv.z + xv.w * xv.w;
#pragma unroll
  for (int off = 32; off >= 1; off >>= 1) {
    s  += __shfl_xor(s, off);
    ss += __shfl_xor(ss, off);
  }
  __shared__ float red[2][4];
  const int w = tid >> 6;
  if ((tid & 63) == 0) { red[0][w] = s; red[1][w] = ss; }
  __syncthreads();
  const float tot  = red[0][0] + red[0][1] + red[0][2] + red[0][3];
  const float tot2 = red[1][0] + red[1][1] + red[1][2] + red[1][3];
  const float mu   = tot * (1.0f / H);
  const float var  = tot2 * (1.0f / H) - mu * mu;
  const float rstd = rsqrtf(var + 1e-5f);
  const float4 g  = reinterpret_cast<const float4*>(gamma)[tid];
  const float4 bt = reinterpret_cast<const float4*>(beta)[tid];
  ushort4 o;
  o.x = f2bf((xv.x - mu) * rstd * g.x + bt.x);
  o.y = f2bf((xv.y - mu) * rstd * g.y + bt.y);
  o.z = f2bf((xv.z - mu) * rstd * g.z + bt.z);
  o.w = f2bf((xv.w - mu) * rstd * g.w + bt.w);
  reinterpret_cast<ushort4*>(xb + (size_t)row * H)[tid] = o;
}

// ---------------- Kernel 2: W -> bf16 ----------------
__global__ __launch_bounds__(256) void wcvt_kernel(
    const float* __restrict__ Win, unsigned short* __restrict__ wb) {
  const size_t i = (size_t)blockIdx.x * 1024 + (size_t)threadIdx.x * 4;
  const float4 xv = *reinterpret_cast<const float4*>(Win + i);
  ushort4 o;
  o.x = f2bf(xv.x); o.y = f2bf(xv.y); o.z = f2bf(xv.z); o.w = f2bf(xv.w);
  *reinterpret_cast<ushort4*>(wb + i) = o;
}

// ---------------- Kernel 3: fused scores GEMM (256x256 tile, 8 waves) ----
// spart[nt][m] = sum_{d in [nt*256,nt*256+256)} tanh(Wout[m,d]+bW[d])*v[d]
__global__ __launch_bounds__(512, 2) void score_gemm(
    const unsigned short* __restrict__ xb, const unsigned short* __restrict__ wb,
    const float* __restrict__ bW, const float* __restrict__ v,
    float* __restrict__ spart) {
  // [2 dbuf][2 khalf][256 rows][32 k] bf16 per matrix = 64 KiB each
  __shared__ unsigned short As[32768];
  __shared__ unsigned short Bs[32768];
  __shared__ float s_red[4][256];

  const int tid  = threadIdx.x;
  const int w    = tid >> 6, lane = tid & 63;
  const int wm   = w >> 2, wn = w & 3;      // 2 M-waves x 4 N-waves

  // bijective XCD swizzle (512 blocks % 8 == 0)
  const int bid0 = blockIdx.x;
  const int bid  = (bid0 & 7) * 64 + (bid0 >> 3);
  const int mt = bid & 127, nt = bid >> 7;
  const int mbase = mt * 256, nbase = nt * 256;

  // --- staging geometry: one half = 256 rows x 32 k = 16 chunks of 1024B ---
  const int srow = lane >> 2;                                  // row in chunk
  const int swz8 = ((lane & 3) ^ ((lane >> 3) & 3)) * 8;       // pre-swizzled src col (bf16)
  const int ch0 = w, ch1 = 8 + w;                              // this wave's chunks

  const unsigned short* gA = xb + (size_t)mbase * H;
  const unsigned short* gB = wb + (size_t)nbase * H;

  auto stage_half = [&](const unsigned short* gbase, unsigned short* lbase,
                        int tk, int kh, int buf) {
    const int ro   = (buf * 2 + kh) * 8192;
    const int gcol = tk * 64 + kh * 32 + swz8;
    GLDS(gbase + (size_t)(ch0 * 16 + srow) * H + gcol, &lbase[ro + ch0 * 512]);
    GLDS(gbase + (size_t)(ch1 * 16 + srow) * H + gcol, &lbase[ro + ch1 * 512]);
  };
  auto stage_set = [&](int tk, int kh, int buf) {   // 4 GLDS / thread
    stage_half(gA, As, tk, kh, buf);
    stage_half(gB, Bs, tk, kh, buf);
  };

  // --- fragment-read geometry (swizzle-matched) ---
  const int acoff = (((lane >> 4) ^ (((lane & 15) >> 1) & 3)) * 8);
  const int arow0 = wm * 128 + (lane & 15);
  const int brow0 = wn * 64  + (lane & 15);

  f32x4 acc[8][4];
#pragma unroll
  for (int mi = 0; mi < 8; mi++)
#pragma unroll
    for (int ni = 0; ni < 4; ni++) acc[mi][ni] = (f32x4){0.f, 0.f, 0.f, 0.f};

  // prologue: tile0 both halves + tile1 khalf0  (12 GLDS out, wait to <=4)
  stage_set(0, 0, 0);
  stage_set(0, 1, 0);
  stage_set(1, 0, 1);
  asm volatile("s_waitcnt vmcnt(4)" ::: "memory");
  __builtin_amdgcn_s_barrier();
  asm volatile("" ::: "memory");

  for (int t = 0; t < NT; t++) {
    const int cur = t & 1;
    // ---- phase 0: khalf 0 ----
    {
      bf16x8 af[8], bf[4];
      const int ro = (cur * 2 + 0) * 8192;
#pragma unroll
      for (int fr = 0; fr < 8; fr++)
        af[fr] = *reinterpret_cast<const bf16x8*>(&As[ro + (arow0 + fr * 16) * 32 + acoff]);
#pragma unroll
      for (int ni = 0; ni < 4; ni++)
        bf[ni] = *reinterpret_cast<const bf16x8*>(&Bs[ro + (brow0 + ni * 16) * 32 + acoff]);
      if (t + 1 < NT) stage_set(t + 1, 1, cur ^ 1);
      __builtin_amdgcn_s_barrier();
      asm volatile("s_waitcnt lgkmcnt(0)" ::: "memory");
      __builtin_amdgcn_sched_barrier(0);
      __builtin_amdgcn_s_setprio(1);
#pragma unroll
      for (int mi = 0; mi < 8; mi++)
#pragma unroll
        for (int ni = 0; ni < 4; ni++)
          acc[mi][ni] = __builtin_amdgcn_mfma_f32_16x16x32_bf16(af[mi], bf[ni], acc[mi][ni], 0, 0, 0);
      __builtin_amdgcn_s_setprio(0);
      __builtin_amdgcn_s_barrier();
      asm volatile("" ::: "memory");
    }
    // ---- phase 1: khalf 1 ----
    {
      bf16x8 af[8], bf[4];
      const int ro = (cur * 2 + 1) * 8192;
#pragma unroll
      for (int fr = 0; fr < 8; fr++)
        af[fr] = *reinterpret_cast<const bf16x8*>(&As[ro + (arow0 + fr * 16) * 32 + acoff]);
#pragma unroll
      for (int ni = 0; ni < 4; ni++)
        bf[ni] = *reinterpret_cast<const bf16x8*>(&Bs[ro + (brow0 + ni * 16) * 32 + acoff]);
      if (t + 2 < NT) stage_set(t + 2, 0, cur);
      __builtin_amdgcn_s_barrier();
      asm volatile("s_waitcnt lgkmcnt(0)" ::: "memory");
      __builtin_amdgcn_sched_barrier(0);
      __builtin_amdgcn_s_setprio(1);
#pragma unroll
      for (int mi = 0; mi < 8; mi++)
#pragma unroll
        for (int ni = 0; ni < 4; ni++)
          acc[mi][ni] = __builtin_amdgcn_mfma_f32_16x16x32_bf16(af[mi], bf[ni], acc[mi][ni], 0, 0, 0);
      __builtin_amdgcn_s_setprio(0);
      // K-tile boundary: counted wait — entire next tile confirmed, 4 loads
      // stay in flight (except at the tail, where nothing further is staged)
      if (t < NT - 2) asm volatile("s_waitcnt vmcnt(4)" ::: "memory");
      else            asm volatile("s_waitcnt vmcnt(0)" ::: "memory");
      __builtin_amdgcn_s_barrier();
      asm volatile("" ::: "memory");
    }
  }

  // ---- epilogue: tanh(.+bW)*v, reduce over N within block ----
  float sp[8][4];
#pragma unroll
  for (int mi = 0; mi < 8; mi++)
#pragma unroll
    for (int r = 0; r < 4; r++) sp[mi][r] = 0.f;

#pragma unroll
  for (int ni = 0; ni < 4; ni++) {
    const int col = nbase + wn * 64 + ni * 16 + (lane & 15);
    const float bwv = bW[col];
    const float vv  = v[col];
#pragma unroll
    for (int mi = 0; mi < 8; mi++)
#pragma unroll
      for (int r = 0; r < 4; r++) {
        float xv = acc[mi][ni][r] + bwv;
        xv = fminf(fmaxf(xv, -15.f), 15.f);
        const float e = __expf(2.f * xv);
        sp[mi][r] += vv * (e - 1.f) / (e + 1.f);   // tanh
      }
  }
#pragma unroll
  for (int mi = 0; mi < 8; mi++)
#pragma unroll
    for (int r = 0; r < 4; r++) {
      float sv = sp[mi][r];
      sv += __shfl_xor(sv, 1);
      sv += __shfl_xor(sv, 2);
      sv += __shfl_xor(sv, 4);
      sv += __shfl_xor(sv, 8);
      sp[mi][r] = sv;
    }
  if ((lane & 15) == 0) {
#pragma unroll
    for (int mi = 0; mi < 8; mi++)
#pragma unroll
      for (int r = 0; r < 4; r++)
        s_red[wn][wm * 128 + mi * 16 + (lane >> 4) * 4 + r] = sp[mi][r];
  }
  __syncthreads();
  if (tid < 256)
    spart[(size_t)nt * BT + mbase + tid] =
        s_red[0][tid] + s_red[1][tid] + s_red[2][tid] + s_red[3][tid];
}

// ---------------- Kernel 4: softmax over T per batch ----------------
__global__ __launch_bounds__(512) void softmax_kernel(
    const float* __restrict__ spart, const float* __restrict__ bv,
    float* __restrict__ wout) {
  const int b = blockIdx.x, t = threadIdx.x;
  float s = bv[0];
#pragma unroll
  for (int p = 0; p < NSPLIT; p++) s += spart[(size_t)p * BT + b * TT + t];
  if (s != s) s = 0.f;                       // nan_to_num
  s = fminf(fmaxf(s, -10.f), 10.f);          // clip
  float m = s;
#pragma unroll
  for (int off = 32; off >= 1; off >>= 1) m = fmaxf(m, __shfl_xor(m, off));
  __shared__ float redm[8], reds[8];
  const int w = t >> 6;
  if ((t & 63) == 0) redm[w] = m;
  __syncthreads();
  m = redm[0];
#pragma unroll
  for (int i = 1; i < 8; i++) m = fmaxf(m, redm[i]);
  const float e = expf(s - m);
  float su = e;
#pragma unroll
  for (int off = 32; off >= 1; off >>= 1) su += __shfl_xor(su, off);
  if ((t & 63) == 0) reds[w] = su;
  __syncthreads();
  su = 0.f;
#pragma unroll
  for (int i = 0; i < 8; i++) su += reds[i];
  wout[b * TT + t] = e / su;
}

// ---------------- Kernel 5: context partials over t-chunks ----------------
__global__ __launch_bounds__(256) void ctx_part_kernel(
    const unsigned short* __restrict__ xb, const float* __restrict__ wts,
    float* __restrict__ ctxp) {
  const int b = blockIdx.x, c = blockIdx.y, tid = threadIdx.x;
  const int h = tid * 4;
  float a0 = 0.f, a1 = 0.f, a2 = 0.f, a3 = 0.f;
  const unsigned short* xrow = xb + ((size_t)(b * TT + c * 64)) * H + h;
  const float* wrow = wts + b * TT + c * 64;
  for (int t = 0; t < 64; t++) {
    const float wgt = wrow[t];
    const ushort4 xv = *reinterpret_cast<const ushort4*>(xrow + (size_t)t * H);
    a0 += wgt * bf2f(xv.x);
    a1 += wgt * bf2f(xv.y);
    a2 += wgt * bf2f(xv.z);
    a3 += wgt * bf2f(xv.w);
  }
  float4 o = {a0, a1, a2, a3};
  *reinterpret_cast<float4*>(ctxp + ((size_t)c * BSZ + b) * H + h) = o;
}

// ---------------- Kernel 6: context reduce ----------------
__global__ __launch_bounds__(256) void ctx_reduce_kernel(
    const float* __restrict__ ctxp, float* __restrict__ out) {
  const int idx = blockIdx.x * 256 + threadIdx.x;  // 0..65535 = b*H+h
  float s = 0.f;
#pragma unroll
  for (int c = 0; c < 8; c++) s += ctxp[(size_t)c * (BSZ * H) + idx];
  out[idx] = s;
}

extern "C" void kernel_launch(void* const* d_in, const int* in_sizes, int n_in,
                              void* d_out, int out_size, void* d_ws, size_t ws_size,
                              hipStream_t stream) {
  const float* lstm  = (const float*)d_in[0];
  const float* W     = (const float*)d_in[1];
  const float* bW    = (const float*)d_in[2];
  const float* v     = (const float*)d_in[3];
  const float* bv    = (const float*)d_in[4];
  const float* gamma = (const float*)d_in[5];
  const float* beta  = (const float*)d_in[6];
  float* out = (float*)d_out;

  char* ws = (char*)d_ws;
  unsigned short* xb = (unsigned short*)ws;                                   // 64 MiB
  unsigned short* wb = (unsigned short*)(ws + (size_t)BT * H * 2);            // 2 MiB
  float* spart = (float*)(ws + (size_t)BT * H * 2 + (size_t)H * H * 2);       // 512 KiB
  float* ctxp  = (float*)((char*)spart + (size_t)NSPLIT * BT * 4);            // 2 MiB

  float* weights_out = out + BSZ * H;   // context first (65536), then weights (32768)

  ln_kernel<<<BT, 256, 0, stream>>>(lstm, gamma, beta, xb);
  wcvt_kernel<<<(H * H) / 1024, 256, 0, stream>>>(W, wb);
  score_gemm<<<512, 512, 0, stream>>>(xb, wb, bW, v, spart);
  softmax_kernel<<<BSZ, TT, 0, stream>>>(spart, bv, weights_out);
  ctx_part_kernel<<<dim3(BSZ, 8), 256, 0, stream>>>(xb, weights_out, ctxp);
  ctx_reduce_kernel<<<(BSZ * H) / 256, 256, 0, stream>>>(ctxp, out);
}